// Round 1
// baseline (231.754 us; speedup 1.0000x reference)
//
#include <hip/hip_runtime.h>
#include <stdint.h>

#define N 8192
#define D 256
#define INV_T 20.0f

typedef __attribute__((ext_vector_type(8))) short bf16x8;
typedef __attribute__((ext_vector_type(4))) float f32x4;

typedef __attribute__((address_space(3))) uint32_t lds_u32;
typedef __attribute__((address_space(1))) const uint32_t gbl_u32;

static __device__ __forceinline__ unsigned short f2bf(float x) {
  unsigned int u = __float_as_uint(x);
  u += 0x7fffu + ((u >> 16) & 1u);           // round-to-nearest-even
  return (unsigned short)(u >> 16);
}

// Kernel 1: per-row normalize (fp32), emit bf16 copies, compute c[i] = (e_i . p_i)/T,
// and zero the 2*N rowsum accumulators (ws is poisoned 0xAA before every launch).
__global__ __launch_bounds__(256) void normalize_kernel(
    const float* __restrict__ e, const float* __restrict__ p, const float* __restrict__ n,
    unsigned short* __restrict__ eb, unsigned short* __restrict__ pb,
    unsigned short* __restrict__ nb, float* __restrict__ cbuf, float* __restrict__ rz) {
  const int tid = threadIdx.x;
  const int wave = tid >> 6, lane = tid & 63;
  const int row = blockIdx.x * 4 + wave;          // one wave per row
  const int gid = blockIdx.x * 256 + tid;
  if (gid < 2 * N) rz[gid] = 0.0f;                // zero rowsum1 ++ rowsum2

  const float4 ev = ((const float4*)(e + (size_t)row * D))[lane];
  const float4 pv = ((const float4*)(p + (size_t)row * D))[lane];
  const float4 nv = ((const float4*)(n + (size_t)row * D))[lane];

  float sse = ev.x*ev.x + ev.y*ev.y + ev.z*ev.z + ev.w*ev.w;
  float ssp = pv.x*pv.x + pv.y*pv.y + pv.z*pv.z + pv.w*pv.w;
  float ssn = nv.x*nv.x + nv.y*nv.y + nv.z*nv.z + nv.w*nv.w;
  float dep = ev.x*pv.x + ev.y*pv.y + ev.z*pv.z + ev.w*pv.w;
#pragma unroll
  for (int m = 1; m < 64; m <<= 1) {
    sse += __shfl_xor(sse, m);
    ssp += __shfl_xor(ssp, m);
    ssn += __shfl_xor(ssn, m);
    dep += __shfl_xor(dep, m);
  }
  const float se = 1.0f / fmaxf(sqrtf(sse), 1e-8f);
  const float sp = 1.0f / fmaxf(sqrtf(ssp), 1e-8f);
  const float sn = 1.0f / fmaxf(sqrtf(ssn), 1e-8f);

  ushort4 ew = { f2bf(ev.x*se), f2bf(ev.y*se), f2bf(ev.z*se), f2bf(ev.w*se) };
  ushort4 pw = { f2bf(pv.x*sp), f2bf(pv.y*sp), f2bf(pv.z*sp), f2bf(pv.w*sp) };
  ushort4 nw = { f2bf(nv.x*sn), f2bf(nv.y*sn), f2bf(nv.z*sn), f2bf(nv.w*sn) };
  ((ushort4*)(eb + (size_t)row * D))[lane] = ew;
  ((ushort4*)(pb + (size_t)row * D))[lane] = pw;
  ((ushort4*)(nb + (size_t)row * D))[lane] = nw;

  if (lane == 0) cbuf[row] = dep * se * sp * INV_T;
}

// Kernel 2: fused 128x128-tile bf16 MFMA GEMM (X @ Y^T) + exp((sim - s_i)/T) row-sums.
// z==0: A=eb, B=nb -> rowsum1;  z==1: A=pb, B=eb -> rowsum2.
// LDS k-octets XOR-swizzled at stage time (global_load_lds forbids padding).
__global__ __launch_bounds__(256) void simexp_kernel(
    const unsigned short* __restrict__ eb, const unsigned short* __restrict__ pb,
    const unsigned short* __restrict__ nb, const float* __restrict__ cbuf,
    float* __restrict__ rowsum1, float* __restrict__ rowsum2) {
  __shared__ unsigned short As[128 * 64];
  __shared__ unsigned short Bs[128 * 64];
  __shared__ float cs[128];

  const int z = blockIdx.z;
  const unsigned short* __restrict__ A = z ? pb : eb;
  const unsigned short* __restrict__ B = z ? eb : nb;
  float* __restrict__ rowsum = z ? rowsum2 : rowsum1;

  const int tid = threadIdx.x;
  const int wave = tid >> 6, lane = tid & 63;
  const int quad = lane >> 4, lane15 = lane & 15;
  const int rowTile = blockIdx.y * 128, colTile = blockIdx.x * 128;
  const int waveRow = (wave & 1) * 64, waveCol = (wave >> 1) * 64;

  if (tid < 128) cs[tid] = cbuf[rowTile + tid];

  f32x4 acc[4][4];
#pragma unroll
  for (int mi = 0; mi < 4; ++mi)
#pragma unroll
    for (int ni = 0; ni < 4; ++ni)
      acc[mi][ni] = (f32x4){0.f, 0.f, 0.f, 0.f};

  for (int k0 = 0; k0 < D; k0 += 64) {
    __syncthreads();   // previous-iteration LDS reads done (also publishes cs on iter 0)
#pragma unroll
    for (int t = 0; t < 4; ++t) {
      const int c = wave * 64 + t * 256 + lane;   // 16B chunk id, lds dst = base + lane*16
      const int r = c >> 3;
      const int og = (c & 7) ^ (r & 7);           // swizzled source octet
      const unsigned short* ga = A + ((size_t)(rowTile + r) * D + k0 + og * 8);
      __builtin_amdgcn_global_load_lds((gbl_u32*)ga, (lds_u32*)&As[c * 8], 16, 0, 0);
      const unsigned short* gb = B + ((size_t)(colTile + r) * D + k0 + og * 8);
      __builtin_amdgcn_global_load_lds((gbl_u32*)gb, (lds_u32*)&Bs[c * 8], 16, 0, 0);
    }
    __syncthreads();   // drains vmcnt -> staged tiles visible

#pragma unroll
    for (int kk = 0; kk < 2; ++kk) {
      const int odb = kk * 4 + quad;              // desired octet within BK=64
      bf16x8 af[4], bfr[4];
#pragma unroll
      for (int mi = 0; mi < 4; ++mi) {
        const int rl = waveRow + mi * 16 + lane15;
        af[mi] = *(const bf16x8*)&As[rl * 64 + ((odb ^ (rl & 7)) * 8)];
        const int cl = waveCol + mi * 16 + lane15;
        bfr[mi] = *(const bf16x8*)&Bs[cl * 64 + ((odb ^ (cl & 7)) * 8)];
      }
#pragma unroll
      for (int mi = 0; mi < 4; ++mi)
#pragma unroll
        for (int ni = 0; ni < 4; ++ni)
          acc[mi][ni] =
              __builtin_amdgcn_mfma_f32_16x16x32_bf16(af[mi], bfr[ni], acc[mi][ni], 0, 0, 0);
    }
  }

  // Epilogue: C/D layout col=lane&15, row=quad*4+reg (verified m89/m91).
  // exp((sim - s_i)/T), sum over this wave's 64 columns, one atomic per row-group.
#pragma unroll
  for (int mi = 0; mi < 4; ++mi) {
    const int rl = waveRow + mi * 16 + quad * 4;
#pragma unroll
    for (int r = 0; r < 4; ++r) {
      const float cv = cs[rl + r];
      float v = 0.0f;
#pragma unroll
      for (int ni = 0; ni < 4; ++ni)
        v += __expf(acc[mi][ni][r] * INV_T - cv);
      v += __shfl_xor(v, 1);
      v += __shfl_xor(v, 2);
      v += __shfl_xor(v, 4);
      v += __shfl_xor(v, 8);
      if (lane15 == 0) atomicAdd(&rowsum[rowTile + rl + r], v);
    }
  }
}

// Kernel 3: loss = mean_i log(1 + rowsum1[i]) + mean_i log(rowsum2[i])
__global__ __launch_bounds__(256) void reduce_kernel(const float* __restrict__ rs1,
                                                     const float* __restrict__ rs2,
                                                     float* __restrict__ out) {
  __shared__ float sm[4];
  const int tid = threadIdx.x;
  float v = 0.0f;
  for (int i = tid; i < N; i += 256)
    v += logf(1.0f + rs1[i]) + logf(rs2[i]);
#pragma unroll
  for (int m = 1; m < 64; m <<= 1) v += __shfl_xor(v, m);
  if ((tid & 63) == 0) sm[tid >> 6] = v;
  __syncthreads();
  if (tid == 0) out[0] = (sm[0] + sm[1] + sm[2] + sm[3]) * (1.0f / (float)N);
}

extern "C" void kernel_launch(void* const* d_in, const int* in_sizes, int n_in,
                              void* d_out, int out_size, void* d_ws, size_t ws_size,
                              hipStream_t stream) {
  const float* e = (const float*)d_in[0];
  const float* p = (const float*)d_in[1];
  const float* n = (const float*)d_in[2];

  char* w = (char*)d_ws;
  unsigned short* eb = (unsigned short*)w;                       // 4 MB
  unsigned short* pb = eb + (size_t)N * D;                       // 4 MB
  unsigned short* nb = pb + (size_t)N * D;                       // 4 MB
  float* cbuf = (float*)(nb + (size_t)N * D);                    // 32 KB
  float* rs1 = cbuf + N;                                         // 32 KB
  float* rs2 = rs1 + N;                                          // 32 KB

  normalize_kernel<<<N / 4, 256, 0, stream>>>(e, p, n, eb, pb, nb, cbuf, rs1);
  simexp_kernel<<<dim3(64, 64, 2), 256, 0, stream>>>(eb, pb, nb, cbuf, rs1, rs2);
  reduce_kernel<<<1, 256, 0, stream>>>(rs1, rs2, (float*)d_out);
}

// Round 2
// 196.423 us; speedup vs baseline: 1.1799x; 1.1799x over previous
//
#include <hip/hip_runtime.h>
#include <stdint.h>

#define N 8192
#define D 256
#define INV_T 20.0f
#define BM 256
#define BN 128
#define BK 64
#define NXB 64   // number of col-blocks (N / BN)

typedef __attribute__((ext_vector_type(8))) short bf16x8;
typedef __attribute__((ext_vector_type(16))) float f32x16;

typedef __attribute__((address_space(3))) uint32_t lds_u32;
typedef __attribute__((address_space(1))) const uint32_t gbl_u32;

static __device__ __forceinline__ unsigned short f2bf(float x) {
  unsigned int u = __float_as_uint(x);
  u += 0x7fffu + ((u >> 16) & 1u);           // round-to-nearest-even
  return (unsigned short)(u >> 16);
}

// Kernel 1: per-row fp32 normalize -> bf16 copies; c[i] = (e_i . p_i)/T (exact fp32).
__global__ __launch_bounds__(256) void normalize_kernel(
    const float* __restrict__ e, const float* __restrict__ p, const float* __restrict__ n,
    unsigned short* __restrict__ eb, unsigned short* __restrict__ pb,
    unsigned short* __restrict__ nb, float* __restrict__ cbuf) {
  const int tid = threadIdx.x;
  const int wave = tid >> 6, lane = tid & 63;
  const int row = blockIdx.x * 4 + wave;          // one wave per row

  const float4 ev = ((const float4*)(e + (size_t)row * D))[lane];
  const float4 pv = ((const float4*)(p + (size_t)row * D))[lane];
  const float4 nv = ((const float4*)(n + (size_t)row * D))[lane];

  float sse = ev.x*ev.x + ev.y*ev.y + ev.z*ev.z + ev.w*ev.w;
  float ssp = pv.x*pv.x + pv.y*pv.y + pv.z*pv.z + pv.w*pv.w;
  float ssn = nv.x*nv.x + nv.y*nv.y + nv.z*nv.z + nv.w*nv.w;
  float dep = ev.x*pv.x + ev.y*pv.y + ev.z*pv.z + ev.w*pv.w;
#pragma unroll
  for (int m = 1; m < 64; m <<= 1) {
    sse += __shfl_xor(sse, m);
    ssp += __shfl_xor(ssp, m);
    ssn += __shfl_xor(ssn, m);
    dep += __shfl_xor(dep, m);
  }
  const float se = 1.0f / fmaxf(sqrtf(sse), 1e-8f);
  const float sp = 1.0f / fmaxf(sqrtf(ssp), 1e-8f);
  const float sn = 1.0f / fmaxf(sqrtf(ssn), 1e-8f);

  ushort4 ew = { f2bf(ev.x*se), f2bf(ev.y*se), f2bf(ev.z*se), f2bf(ev.w*se) };
  ushort4 pw = { f2bf(pv.x*sp), f2bf(pv.y*sp), f2bf(pv.z*sp), f2bf(pv.w*sp) };
  ushort4 nw = { f2bf(nv.x*sn), f2bf(nv.y*sn), f2bf(nv.z*sn), f2bf(nv.w*sn) };
  ((ushort4*)(eb + (size_t)row * D))[lane] = ew;
  ((ushort4*)(pb + (size_t)row * D))[lane] = pw;
  ((ushort4*)(nb + (size_t)row * D))[lane] = nw;

  if (lane == 0) cbuf[row] = dep * se * sp * INV_T;
}

// Kernel 2: 256x128-tile bf16 GEMM (X @ Y^T) via 32x32x16 MFMA + fused exp row-sums.
// grid (x=rowblk [fast], y=colblk, z): xcd = blk%8 = rowblk%8 -> A-strip pinned per-XCD L2.
// Partial row-sums written (no atomics) to part[z][colblk][row].
__global__ __launch_bounds__(256, 2) void simexp_kernel(
    const unsigned short* __restrict__ eb, const unsigned short* __restrict__ pb,
    const unsigned short* __restrict__ nb, const float* __restrict__ cbuf,
    float* __restrict__ part) {
  __shared__ unsigned short As[BM * BK];   // 32 KB
  __shared__ unsigned short Bs[BN * BK];   // 16 KB
  __shared__ float cs[BM];

  const int z = blockIdx.z;
  const unsigned short* __restrict__ A = z ? pb : eb;
  const unsigned short* __restrict__ B = z ? eb : nb;

  const int tid = threadIdx.x;
  const int wave = tid >> 6, lane = tid & 63;
  const int lane31 = lane & 31, half = lane >> 5;
  const int rowTile = blockIdx.x * BM, colblk = blockIdx.y;
  const int colTile = colblk * BN;

  cs[tid] = cbuf[rowTile + tid];           // 256 threads, 256 rows

  f32x16 acc[2][4];
#pragma unroll
  for (int mi = 0; mi < 2; ++mi)
#pragma unroll
    for (int ni = 0; ni < 4; ++ni)
#pragma unroll
      for (int r = 0; r < 16; ++r) acc[mi][ni][r] = 0.0f;

  for (int k0 = 0; k0 < D; k0 += BK) {
    __syncthreads();   // LDS reuse guard (also publishes cs on iter 0)
#pragma unroll
    for (int t = 0; t < 8; ++t) {          // A: 256x64 = 2048 16B-chunks
      const int c = t * 256 + tid;
      const int r = c >> 3;
      const int og = (c & 7) ^ (r & 7);    // XOR-swizzled source octet
      const unsigned short* ga = A + ((size_t)(rowTile + r) * D + k0 + og * 8);
      __builtin_amdgcn_global_load_lds((gbl_u32*)ga, (lds_u32*)&As[c * 8], 16, 0, 0);
    }
#pragma unroll
    for (int t = 0; t < 4; ++t) {          // B: 128x64 = 1024 16B-chunks
      const int c = t * 256 + tid;
      const int r = c >> 3;
      const int og = (c & 7) ^ (r & 7);
      const unsigned short* gb = B + ((size_t)(colTile + r) * D + k0 + og * 8);
      __builtin_amdgcn_global_load_lds((gbl_u32*)gb, (lds_u32*)&Bs[c * 8], 16, 0, 0);
    }
    __syncthreads();   // drain -> tiles visible

#pragma unroll
    for (int s = 0; s < 4; ++s) {          // 4 k-steps of 16
      const int odb = s * 2 + half;        // this lane's k-octet within BK
      bf16x8 af[2], bfr[4];
#pragma unroll
      for (int mi = 0; mi < 2; ++mi) {
        const int rl = wave * 64 + mi * 32 + lane31;
        af[mi] = *(const bf16x8*)&As[rl * BK + ((odb ^ (rl & 7)) * 8)];
      }
#pragma unroll
      for (int ni = 0; ni < 4; ++ni) {
        const int cl = ni * 32 + lane31;
        bfr[ni] = *(const bf16x8*)&Bs[cl * BK + ((odb ^ (cl & 7)) * 8)];
      }
#pragma unroll
      for (int mi = 0; mi < 2; ++mi)
#pragma unroll
        for (int ni = 0; ni < 4; ++ni)
          acc[mi][ni] =
              __builtin_amdgcn_mfma_f32_32x32x16_bf16(af[mi], bfr[ni], acc[mi][ni], 0, 0, 0);
    }
  }

  // Epilogue. 32x32 C/D: col=lane&31, row=(reg&3)+8*(reg>>2)+4*(lane>>5) (m74/m101).
#pragma unroll
  for (int mi = 0; mi < 2; ++mi) {
#pragma unroll
    for (int reg = 0; reg < 16; ++reg) {
      const int rlocal = (reg & 3) + 8 * (reg >> 2) + 4 * half;
      const int rowl = wave * 64 + mi * 32 + rlocal;
      const float cv = cs[rowl];
      float v = 0.0f;
#pragma unroll
      for (int ni = 0; ni < 4; ++ni)
        v += __expf(acc[mi][ni][reg] * INV_T - cv);
      v += __shfl_xor(v, 1);
      v += __shfl_xor(v, 2);
      v += __shfl_xor(v, 4);
      v += __shfl_xor(v, 8);
      v += __shfl_xor(v, 16);
      if (lane31 == 0)
        part[((size_t)(z * NXB + colblk)) * N + rowTile + rowl] = v;
    }
  }
}

// Kernel 3: per-row sum of 64 partials -> log/log1p -> per-block partial loss.
__global__ __launch_bounds__(128) void reduce1_kernel(const float* __restrict__ part,
                                                      float* __restrict__ partials) {
  const int bid = blockIdx.x;              // 128 blocks
  const int z = bid >> 6;
  const int row = (bid & 63) * 128 + threadIdx.x;
  float s = 0.0f;
#pragma unroll 8
  for (int x = 0; x < NXB; ++x)
    s += part[((size_t)(z * NXB + x)) * N + row];
  float val = z ? logf(s) : log1pf(s);
#pragma unroll
  for (int m = 1; m < 64; m <<= 1) val += __shfl_xor(val, m);
  __shared__ float sm[2];
  if ((threadIdx.x & 63) == 0) sm[threadIdx.x >> 6] = val;
  __syncthreads();
  if (threadIdx.x == 0) partials[bid] = sm[0] + sm[1];
}

// Kernel 4: final 128-way sum -> mean loss.
__global__ __launch_bounds__(128) void reduce2_kernel(const float* __restrict__ partials,
                                                      float* __restrict__ out) {
  float v = partials[threadIdx.x];
#pragma unroll
  for (int m = 1; m < 64; m <<= 1) v += __shfl_xor(v, m);
  __shared__ float sm[2];
  if ((threadIdx.x & 63) == 0) sm[threadIdx.x >> 6] = v;
  __syncthreads();
  if (threadIdx.x == 0) out[0] = (sm[0] + sm[1]) * (1.0f / (float)N);
}

extern "C" void kernel_launch(void* const* d_in, const int* in_sizes, int n_in,
                              void* d_out, int out_size, void* d_ws, size_t ws_size,
                              hipStream_t stream) {
  const float* e = (const float*)d_in[0];
  const float* p = (const float*)d_in[1];
  const float* n = (const float*)d_in[2];

  char* w = (char*)d_ws;
  unsigned short* eb = (unsigned short*)w;                       // 4 MB
  unsigned short* pb = eb + (size_t)N * D;                       // 4 MB
  unsigned short* nb = pb + (size_t)N * D;                       // 4 MB
  float* cbuf = (float*)(nb + (size_t)N * D);                    // 32 KB
  float* part = cbuf + N;                                        // 2*64*8192*4 = 4 MB
  float* partials = part + (size_t)2 * NXB * N;                  // 512 B

  normalize_kernel<<<N / 4, 256, 0, stream>>>(e, p, n, eb, pb, nb, cbuf);
  simexp_kernel<<<dim3(N / BM, N / BN, 2), 256, 0, stream>>>(eb, pb, nb, cbuf, part);
  reduce1_kernel<<<128, 128, 0, stream>>>(part, partials);
  reduce2_kernel<<<1, 128, 0, stream>>>(partials, (float*)d_out);
}

// Round 3
// 147.424 us; speedup vs baseline: 1.5720x; 1.3324x over previous
//
#include <hip/hip_runtime.h>
#include <stdint.h>

#define N 8192
#define D 256          // elements per row == bytes per fp8 row
#define INV_T 20.0f
#define BM 128
#define BN 128
#define BK 64
#define NXB 64         // col-blocks (N/BN)

typedef __attribute__((ext_vector_type(16))) float f32x16;
typedef __attribute__((ext_vector_type(2))) long i64x2;

typedef __attribute__((address_space(3))) uint32_t lds_u32;
typedef __attribute__((address_space(1))) const uint32_t gbl_u32;

// Kernel 1: per-row fp32 normalize -> fp8 e4m3 copies (HW cvt, OCP on gfx950);
// c[i] = (e_i . p_i)/T exact fp32.
__global__ __launch_bounds__(256) void normalize_kernel(
    const float* __restrict__ e, const float* __restrict__ p, const float* __restrict__ n,
    uint32_t* __restrict__ eb, uint32_t* __restrict__ pb, uint32_t* __restrict__ nb,
    float* __restrict__ cbuf) {
  const int tid = threadIdx.x;
  const int wave = tid >> 6, lane = tid & 63;
  const int row = blockIdx.x * 4 + wave;          // one wave per row

  const float4 ev = ((const float4*)(e + (size_t)row * D))[lane];
  const float4 pv = ((const float4*)(p + (size_t)row * D))[lane];
  const float4 nv = ((const float4*)(n + (size_t)row * D))[lane];

  float sse = ev.x*ev.x + ev.y*ev.y + ev.z*ev.z + ev.w*ev.w;
  float ssp = pv.x*pv.x + pv.y*pv.y + pv.z*pv.z + pv.w*pv.w;
  float ssn = nv.x*nv.x + nv.y*nv.y + nv.z*nv.z + nv.w*nv.w;
  float dep = ev.x*pv.x + ev.y*pv.y + ev.z*pv.z + ev.w*pv.w;
#pragma unroll
  for (int m = 1; m < 64; m <<= 1) {
    sse += __shfl_xor(sse, m);
    ssp += __shfl_xor(ssp, m);
    ssn += __shfl_xor(ssn, m);
    dep += __shfl_xor(dep, m);
  }
  const float se = 1.0f / fmaxf(sqrtf(sse), 1e-8f);
  const float sp = 1.0f / fmaxf(sqrtf(ssp), 1e-8f);
  const float sn = 1.0f / fmaxf(sqrtf(ssn), 1e-8f);

  int ue = __builtin_amdgcn_cvt_pk_fp8_f32(ev.x*se, ev.y*se, 0, false);
  ue     = __builtin_amdgcn_cvt_pk_fp8_f32(ev.z*se, ev.w*se, ue, true);
  int up = __builtin_amdgcn_cvt_pk_fp8_f32(pv.x*sp, pv.y*sp, 0, false);
  up     = __builtin_amdgcn_cvt_pk_fp8_f32(pv.z*sp, pv.w*sp, up, true);
  int un = __builtin_amdgcn_cvt_pk_fp8_f32(nv.x*sn, nv.y*sn, 0, false);
  un     = __builtin_amdgcn_cvt_pk_fp8_f32(nv.z*sn, nv.w*sn, un, true);
  eb[row * 64 + lane] = (uint32_t)ue;             // 64 uints = 256 fp8 bytes per row
  pb[row * 64 + lane] = (uint32_t)up;
  nb[row * 64 + lane] = (uint32_t)un;

  if (lane == 0) cbuf[row] = dep * se * sp * INV_T;
}

// Kernel 2: 128x128-tile fp8 GEMM (X @ Y^T), 32x32x16_fp8_fp8 MFMA, fused exp row-sums.
// LDS swizzle: 16B-group gg of row r stored at slot gg ^ ((r>>1)&3) -> 8 consecutive
// rows' b128 reads tile all 32 banks exactly once (conflict-free). The resulting
// K-order permutation is applied identically to A and B -> dot product unchanged.
__global__ __launch_bounds__(256, 4) void simexp_kernel(
    const uint8_t* __restrict__ eb, const uint8_t* __restrict__ pb,
    const uint8_t* __restrict__ nb, const float* __restrict__ cbuf,
    float* __restrict__ part) {
  __shared__ uint8_t As[BM * BK];   // 8 KB
  __shared__ uint8_t Bs[BN * BK];   // 8 KB
  __shared__ float cs[BM];          // 512 B

  const int z = blockIdx.z;
  const uint8_t* __restrict__ A = z ? pb : eb;
  const uint8_t* __restrict__ B = z ? eb : nb;

  const int tid = threadIdx.x;
  const int wave = tid >> 6, lane = tid & 63;
  const int lane31 = lane & 31, half = lane >> 5;
  const int rowTile = blockIdx.x * BM, colblk = blockIdx.y;
  const int colTile = colblk * BN;
  const int rl = wave * 32 + lane31;              // this lane's A row (local)

  if (tid < BM) cs[tid] = cbuf[rowTile + tid];

  f32x16 acc[4];
#pragma unroll
  for (int ni = 0; ni < 4; ++ni)
#pragma unroll
    for (int r = 0; r < 16; ++r) acc[ni][r] = 0.0f;

#pragma unroll
  for (int k0i = 0; k0i < 4; ++k0i) {
    const int k0 = k0i * BK;
    __syncthreads();   // LDS reuse guard (publishes cs on iter 0)
#pragma unroll
    for (int t = 0; t < 2; ++t) {                 // A: 128x64B = 512 16B-chunks
      const int c = t * 256 + tid;
      const int r = c >> 2, sl = c & 3;
      const int gg = sl ^ ((r >> 1) & 3);         // swizzled SOURCE group
      __builtin_amdgcn_global_load_lds(
          (gbl_u32*)(A + (size_t)(rowTile + r) * D + k0 + gg * 16),
          (lds_u32*)&As[c * 16], 16, 0, 0);
    }
#pragma unroll
    for (int t = 0; t < 2; ++t) {                 // B: 512 16B-chunks
      const int c = t * 256 + tid;
      const int r = c >> 2, sl = c & 3;
      const int gg = sl ^ ((r >> 1) & 3);
      __builtin_amdgcn_global_load_lds(
          (gbl_u32*)(B + (size_t)(colTile + r) * D + k0 + gg * 16),
          (lds_u32*)&Bs[c * 16], 16, 0, 0);
    }
    __syncthreads();   // drain -> tiles visible

#pragma unroll
    for (int g = 0; g < 2; ++g) {
      const int gga = half * 2 + g;               // this lane's logical 16B-group
      const i64x2 av = *(const i64x2*)&As[rl * BK + ((gga ^ ((rl >> 1) & 3)) * 16)];
      i64x2 bv[4];
#pragma unroll
      for (int ni = 0; ni < 4; ++ni) {
        const int cl = ni * 32 + lane31;
        bv[ni] = *(const i64x2*)&Bs[cl * BK + ((gga ^ ((cl >> 1) & 3)) * 16)];
      }
#pragma unroll
      for (int ni = 0; ni < 4; ++ni)
        acc[ni] = __builtin_amdgcn_mfma_f32_32x32x16_fp8_fp8(av.x, bv[ni].x, acc[ni], 0, 0, 0);
#pragma unroll
      for (int ni = 0; ni < 4; ++ni)
        acc[ni] = __builtin_amdgcn_mfma_f32_32x32x16_fp8_fp8(av.y, bv[ni].y, acc[ni], 0, 0, 0);
    }
  }

  // Epilogue. 32x32 C/D: col=lane&31, row=(reg&3)+8*(reg>>2)+4*(lane>>5) (m74/m101).
#pragma unroll
  for (int reg = 0; reg < 16; ++reg) {
    const int rlocal = (reg & 3) + 8 * (reg >> 2) + 4 * half;
    const int rowl = wave * 32 + rlocal;
    const float cv = cs[rowl];
    float v = 0.0f;
#pragma unroll
    for (int ni = 0; ni < 4; ++ni)
      v += __expf(acc[ni][reg] * INV_T - cv);
    v += __shfl_xor(v, 1);
    v += __shfl_xor(v, 2);
    v += __shfl_xor(v, 4);
    v += __shfl_xor(v, 8);
    v += __shfl_xor(v, 16);
    if (lane31 == 0)
      part[((size_t)(z * NXB + colblk)) * N + rowTile + rowl] = v;
  }
}

// Kernel 3: per-row sum of 64 partials -> log/log1p -> 64 block partials.
__global__ __launch_bounds__(256) void reduce1_kernel(const float* __restrict__ part,
                                                      float* __restrict__ partials) {
  const int bid = blockIdx.x;              // 64 blocks
  const int z = bid >> 5;
  const int row = (bid & 31) * 256 + threadIdx.x;
  float s = 0.0f;
#pragma unroll 8
  for (int x = 0; x < NXB; ++x)
    s += part[((size_t)(z * NXB + x)) * N + row];
  float val = z ? logf(s) : log1pf(s);
#pragma unroll
  for (int m = 1; m < 64; m <<= 1) val += __shfl_xor(val, m);
  __shared__ float sm[4];
  if ((threadIdx.x & 63) == 0) sm[threadIdx.x >> 6] = val;
  __syncthreads();
  if (threadIdx.x == 0) partials[bid] = sm[0] + sm[1] + sm[2] + sm[3];
}

// Kernel 4: final 64-way sum -> mean loss.
__global__ __launch_bounds__(64) void reduce2_kernel(const float* __restrict__ partials,
                                                     float* __restrict__ out) {
  float v = partials[threadIdx.x];
#pragma unroll
  for (int m = 1; m < 64; m <<= 1) v += __shfl_xor(v, m);
  if (threadIdx.x == 0) out[0] = v * (1.0f / (float)N);
}

extern "C" void kernel_launch(void* const* d_in, const int* in_sizes, int n_in,
                              void* d_out, int out_size, void* d_ws, size_t ws_size,
                              hipStream_t stream) {
  const float* e = (const float*)d_in[0];
  const float* p = (const float*)d_in[1];
  const float* n = (const float*)d_in[2];

  char* w = (char*)d_ws;
  uint8_t* eb = (uint8_t*)w;                                     // 2 MB
  uint8_t* pb = eb + (size_t)N * D;                              // 2 MB
  uint8_t* nb = pb + (size_t)N * D;                              // 2 MB
  float* cbuf = (float*)(nb + (size_t)N * D);                    // 32 KB
  float* part = cbuf + N;                                        // 4 MB
  float* partials = part + (size_t)2 * NXB * N;                  // 256 B

  normalize_kernel<<<N / 4, 256, 0, stream>>>(e, p, n, (uint32_t*)eb, (uint32_t*)pb,
                                              (uint32_t*)nb, cbuf);
  simexp_kernel<<<dim3(N / BM, N / BN, 2), 256, 0, stream>>>(eb, pb, nb, cbuf, part);
  reduce1_kernel<<<64, 256, 0, stream>>>(part, partials);
  reduce2_kernel<<<1, 64, 0, stream>>>(partials, (float*)d_out);
}